// Round 1
// baseline (133.287 us; speedup 1.0000x reference)
//
#include <hip/hip_runtime.h>

#define BATCH   1024
#define NF      64
#define EDIM    64
#define ADIM    32
#define NPAIR   2016        // 64*63/2
#define XSTR    65          // padded LDS stride: bank = (i + e) % 32, conflict-free

__global__ __launch_bounds__(256) void afm_kernel(
    const float* __restrict__ emb,    // (B, NF, E)
    const float* __restrict__ W1,     // (E, A)
    const float* __restrict__ b1,     // (A)
    const float* __restrict__ W2,     // (A, 1)
    const float* __restrict__ b2,     // (1)
    float* __restrict__ out_vec,      // (B, E)
    float* __restrict__ out_attn)     // (B, NPAIR)
{
    __shared__ float xs[NF * XSTR];
    __shared__ float logits[NPAIR];          // reused: logits -> exp -> attn
    __shared__ unsigned short pairIJ[NPAIR]; // (i << 8) | j
    __shared__ float red[8];
    __shared__ float partial[4][EDIM];

    const int t    = threadIdx.x;
    const int b    = blockIdx.x;
    const int wid  = t >> 6;
    const int lane = t & 63;

    // ---- stage x into LDS (padded) ----
    const float* xg = emb + (size_t)b * NF * EDIM;
    for (int idx = t; idx < NF * EDIM; idx += 256) {
        int f = idx >> 6, e = idx & 63;
        xs[f * XSTR + e] = xg[idx];
    }

    // ---- pair index table (same order as np.triu_indices(64, k=1)) ----
    for (int p = t; p < NPAIR; p += 256) {
        float fp = (float)p;
        int i = (int)((127.0f - sqrtf(16129.0f - 8.0f * fp)) * 0.5f);
        if (i < 0) i = 0;
        if (i > NF - 2) i = NF - 2;
        while (i < NF - 2 && (i + 1) * (2 * NF - i - 2) / 2 <= p) ++i;
        while (i > 0 && i * (2 * NF - i - 1) / 2 > p) --i;
        int j = p - i * (2 * NF - i - 1) / 2 + i + 1;
        pairIJ[p] = (unsigned short)((i << 8) | j);
    }
    __syncthreads();

    // ---- phase 1: logits[p] = relu(inner_p . W1 + b1) . W2 + b2 ----
    // W1/b1/W2/b2 have wave-uniform addresses -> scalar loads via k$.
    for (int p = t; p < NPAIR; p += 256) {
        int ij = pairIJ[p];
        const float* xi = &xs[(ij >> 8) * XSTR];
        const float* xj = &xs[(ij & 255) * XSTR];
        float acc[ADIM];
        #pragma unroll
        for (int a = 0; a < ADIM; ++a) acc[a] = b1[a];
        #pragma unroll 4
        for (int e = 0; e < EDIM; ++e) {
            float prod = xi[e] * xj[e];
            #pragma unroll
            for (int a = 0; a < ADIM; ++a)
                acc[a] = fmaf(prod, W1[e * ADIM + a], acc[a]);
        }
        float logit = b2[0];
        #pragma unroll
        for (int a = 0; a < ADIM; ++a)
            logit = fmaf(fmaxf(acc[a], 0.0f), W2[a], logit);
        logits[p] = logit;
    }
    __syncthreads();

    // ---- phase 2: softmax over the 2016 pairs ----
    float m = -INFINITY;
    for (int p = t; p < NPAIR; p += 256) m = fmaxf(m, logits[p]);
    #pragma unroll
    for (int off = 32; off; off >>= 1) m = fmaxf(m, __shfl_xor(m, off));
    if (lane == 0) red[wid] = m;
    __syncthreads();
    if (t == 0) red[4] = fmaxf(fmaxf(red[0], red[1]), fmaxf(red[2], red[3]));
    __syncthreads();
    m = red[4];

    float s = 0.0f;
    for (int p = t; p < NPAIR; p += 256) {
        float ev = __expf(logits[p] - m);
        logits[p] = ev;            // own slot only, no cross-thread hazard
        s += ev;
    }
    #pragma unroll
    for (int off = 32; off; off >>= 1) s += __shfl_xor(s, off);
    __syncthreads();               // everyone done reading red[4]
    if (lane == 0) red[wid] = s;
    __syncthreads();
    if (t == 0) red[5] = red[0] + red[1] + red[2] + red[3];
    __syncthreads();
    const float inv = 1.0f / red[5];

    for (int p = t; p < NPAIR; p += 256) {
        float av = logits[p] * inv;
        logits[p] = av;
        out_attn[(size_t)b * NPAIR + p] = av;
    }
    __syncthreads();

    // ---- phase 3: out[e] = sum_p attn[p] * x_i[e] * x_j[e] ----
    // lane = e (consecutive -> conflict-free); each wave owns 504 pairs.
    float acc = 0.0f;
    const int p0 = wid * (NPAIR / 4);
    const int p1 = p0 + (NPAIR / 4);
    for (int p = p0; p < p1; ++p) {
        int ij = pairIJ[p];                    // broadcast
        float w = logits[p];                   // broadcast
        float xi = xs[(ij >> 8) * XSTR + lane];
        float xj = xs[(ij & 255) * XSTR + lane];
        acc = fmaf(w, xi * xj, acc);
    }
    partial[wid][lane] = acc;
    __syncthreads();
    if (t < EDIM)
        out_vec[(size_t)b * EDIM + t] =
            partial[0][t] + partial[1][t] + partial[2][t] + partial[3][t];
}

extern "C" void kernel_launch(void* const* d_in, const int* in_sizes, int n_in,
                              void* d_out, int out_size, void* d_ws, size_t ws_size,
                              hipStream_t stream) {
    const float* emb = (const float*)d_in[0];
    const float* W1  = (const float*)d_in[1];
    const float* b1  = (const float*)d_in[2];
    const float* W2  = (const float*)d_in[3];
    const float* b2  = (const float*)d_in[4];
    float* out_vec  = (float*)d_out;                        // (B, E)
    float* out_attn = (float*)d_out + (size_t)BATCH * EDIM; // (B, NPAIR)

    afm_kernel<<<BATCH, 256, 0, stream>>>(emb, W1, b1, W2, b2, out_vec, out_attn);
}

// Round 2
// 77.997 us; speedup vs baseline: 1.7089x; 1.7089x over previous
//
#include <hip/hip_runtime.h>

#define BATCH   1024
#define NF      64
#define EDIM    64
#define ADIM    32
#define NPAIR   2016        // 64*63/2
#define NTILE   126         // NPAIR / 16
#define XSTR    68          // padded LDS stride: 272B/row -> 16B aligned, bank rot 4/row

typedef __bf16 bf16_t;
typedef bf16_t bf16x8 __attribute__((ext_vector_type(8)));
typedef float  f32x4  __attribute__((ext_vector_type(4)));

__global__ __launch_bounds__(256) void afm_kernel(
    const float* __restrict__ emb,    // (B, NF, E)
    const float* __restrict__ W1,     // (E, A)
    const float* __restrict__ b1,     // (A)
    const float* __restrict__ W2,     // (A, 1)
    const float* __restrict__ b2,     // (1)
    float* __restrict__ out_vec,      // (B, E)
    float* __restrict__ out_attn)     // (B, NPAIR)
{
    __shared__ __align__(16) float xs[NF * XSTR];
    __shared__ float logits[NPAIR];          // reused: logits -> exp -> attn
    __shared__ unsigned short pairIJ[NPAIR]; // (i << 8) | j
    __shared__ float red[8];
    __shared__ float partial[4][EDIM];

    const int t    = threadIdx.x;
    const int b    = blockIdx.x;
    const int wid  = t >> 6;
    const int lane = t & 63;
    const int g    = lane >> 4;   // quarter-wave group (K/adim-reg group)
    const int m16  = lane & 15;   // pair-within-tile index

    // ---- stage x into LDS (padded rows, float4) ----
    const float4* xg4 = (const float4*)(emb + (size_t)b * NF * EDIM);
    for (int idx = t; idx < NF * EDIM / 4; idx += 256) {
        int f = idx >> 4, e4 = (idx & 15) * 4;
        *(float4*)&xs[f * XSTR + e4] = xg4[idx];
    }

    // ---- pair index table (np.triu_indices(64, k=1) order) ----
    for (int p = t; p < NPAIR; p += 256) {
        float fp = (float)p;
        int i = (int)((127.0f - sqrtf(16129.0f - 8.0f * fp)) * 0.5f);
        if (i < 0) i = 0;
        if (i > NF - 2) i = NF - 2;
        while (i < NF - 2 && (i + 1) * (2 * NF - i - 2) / 2 <= p) ++i;
        while (i > 0 && i * (2 * NF - i - 1) / 2 > p) --i;
        int j = p - i * (2 * NF - i - 1) / 2 + i + 1;
        pairIJ[p] = (unsigned short)((i << 8) | j);
    }

    // ---- W1^T fragments (A-operand), per-lane bias/W2 slices ----
    // A[m=adim nh*16+m16][k=kh*32+8g+j] = W1[(kh*32+8g+j)*ADIM + nh*16+m16]
    bf16x8 w1f[2][2];
    #pragma unroll
    for (int kh = 0; kh < 2; ++kh)
        #pragma unroll
        for (int nh = 0; nh < 2; ++nh)
            #pragma unroll
            for (int j = 0; j < 8; ++j)
                w1f[kh][nh][j] =
                    (bf16_t)W1[(kh * 32 + 8 * g + j) * ADIM + nh * 16 + m16];

    float b1v[2][4], w2v[2][4];
    #pragma unroll
    for (int nh = 0; nh < 2; ++nh)
        #pragma unroll
        for (int r = 0; r < 4; ++r) {
            b1v[nh][r] = b1[nh * 16 + 4 * g + r];
            w2v[nh][r] = W2[nh * 16 + 4 * g + r];
        }
    const float b2s = b2[0];
    __syncthreads();

    // ---- phase 1: logits via MFMA, D = W1^T(32x64) @ inner^T(64x16pairs) ----
    // D row = adim (4g+r), D col = pair (m16) -> adim reduce is in-lane + 2 shfl.
    for (int tile = wid; tile < NTILE; tile += 4) {
        const int p  = tile * 16 + m16;
        const int ij = pairIJ[p];
        const float* xi = &xs[(ij >> 8) * XSTR];
        const float* xj = &xs[(ij & 255) * XSTR];

        f32x4 acc0 = {0.f, 0.f, 0.f, 0.f};
        f32x4 acc1 = {0.f, 0.f, 0.f, 0.f};
        #pragma unroll
        for (int kh = 0; kh < 2; ++kh) {
            const int eb = kh * 32 + 8 * g;
            float4 xa = *(const float4*)(xi + eb);
            float4 xb = *(const float4*)(xi + eb + 4);
            float4 ya = *(const float4*)(xj + eb);
            float4 yb = *(const float4*)(xj + eb + 4);
            bf16x8 bi;
            bi[0] = (bf16_t)(xa.x * ya.x); bi[1] = (bf16_t)(xa.y * ya.y);
            bi[2] = (bf16_t)(xa.z * ya.z); bi[3] = (bf16_t)(xa.w * ya.w);
            bi[4] = (bf16_t)(xb.x * yb.x); bi[5] = (bf16_t)(xb.y * yb.y);
            bi[6] = (bf16_t)(xb.z * yb.z); bi[7] = (bf16_t)(xb.w * yb.w);
            acc0 = __builtin_amdgcn_mfma_f32_16x16x32_bf16(w1f[kh][0], bi, acc0, 0, 0, 0);
            acc1 = __builtin_amdgcn_mfma_f32_16x16x32_bf16(w1f[kh][1], bi, acc1, 0, 0, 0);
        }

        float tr = 0.f;
        #pragma unroll
        for (int r = 0; r < 4; ++r) {
            tr += fmaxf(acc0[r] + b1v[0][r], 0.f) * w2v[0][r];
            tr += fmaxf(acc1[r] + b1v[1][r], 0.f) * w2v[1][r];
        }
        tr += __shfl_xor(tr, 16);
        tr += __shfl_xor(tr, 32);
        if (g == 0) logits[p] = tr + b2s;
    }
    __syncthreads();

    // ---- phase 2: softmax over the 2016 pairs ----
    float m = -INFINITY;
    for (int p = t; p < NPAIR; p += 256) m = fmaxf(m, logits[p]);
    #pragma unroll
    for (int off = 32; off; off >>= 1) m = fmaxf(m, __shfl_xor(m, off));
    if (lane == 0) red[wid] = m;
    __syncthreads();
    if (t == 0) red[4] = fmaxf(fmaxf(red[0], red[1]), fmaxf(red[2], red[3]));
    __syncthreads();
    m = red[4];

    float s = 0.0f;
    for (int p = t; p < NPAIR; p += 256) {
        float ev = __expf(logits[p] - m);
        logits[p] = ev;
        s += ev;
    }
    #pragma unroll
    for (int off = 32; off; off >>= 1) s += __shfl_xor(s, off);
    __syncthreads();
    if (lane == 0) red[wid] = s;
    __syncthreads();
    if (t == 0) red[5] = red[0] + red[1] + red[2] + red[3];
    __syncthreads();
    const float inv = 1.0f / red[5];

    for (int p = t; p < NPAIR; p += 256) {
        float av = logits[p] * inv;
        logits[p] = av;
        out_attn[(size_t)b * NPAIR + p] = av;
    }
    __syncthreads();

    // ---- phase 3: out[e] = sum_p attn[p] * x_i[e] * x_j[e] ----
    // lane = e; bank = (4i + lane) % 32 -> 2 lanes/bank, conflict-free.
    float acc = 0.0f;
    const int p0 = wid * (NPAIR / 4);
    const int p1 = p0 + (NPAIR / 4);
    for (int p = p0; p < p1; ++p) {
        int ij  = pairIJ[p];
        float w = logits[p];
        float xi = xs[(ij >> 8) * XSTR + lane];
        float xj = xs[(ij & 255) * XSTR + lane];
        acc = fmaf(w, xi * xj, acc);
    }
    partial[wid][lane] = acc;
    __syncthreads();
    if (t < EDIM)
        out_vec[(size_t)b * EDIM + t] =
            partial[0][t] + partial[1][t] + partial[2][t] + partial[3][t];
}

extern "C" void kernel_launch(void* const* d_in, const int* in_sizes, int n_in,
                              void* d_out, int out_size, void* d_ws, size_t ws_size,
                              hipStream_t stream) {
    const float* emb = (const float*)d_in[0];
    const float* W1  = (const float*)d_in[1];
    const float* b1  = (const float*)d_in[2];
    const float* W2  = (const float*)d_in[3];
    const float* b2  = (const float*)d_in[4];
    float* out_vec  = (float*)d_out;                        // (B, E)
    float* out_attn = (float*)d_out + (size_t)BATCH * EDIM; // (B, NPAIR)

    afm_kernel<<<BATCH, 256, 0, stream>>>(emb, W1, b1, W2, b2, out_vec, out_attn);
}

// Round 3
// 41.786 us; speedup vs baseline: 3.1898x; 1.8666x over previous
//
#include <hip/hip_runtime.h>

#define BATCH   1024
#define NF      64
#define EDIM    64
#define ADIM    32
#define NPAIR   2016        // 64*63/2
#define NTILE   126         // NPAIR / 16
#define XSTR    72          // bf16 elems/row: 144B rows -> 16B aligned, bank rot 4/row

typedef __bf16 bf16_t;
typedef bf16_t bf16x8 __attribute__((ext_vector_type(8)));
typedef float  f32x4  __attribute__((ext_vector_type(4)));
typedef unsigned short u16;
typedef u16 u16x4 __attribute__((ext_vector_type(4)));

__device__ __forceinline__ float bu(u16 u) {
    union { unsigned int i; float f; } c; c.i = ((unsigned int)u) << 16; return c.f;
}
__device__ __forceinline__ u16 fb(float f) {
    bf16_t h = (bf16_t)f;
    union { bf16_t h; u16 u; } c; c.h = h; return c.u;
}

__global__ __launch_bounds__(256) void afm_kernel(
    const float* __restrict__ emb,    // (B, NF, E)
    const float* __restrict__ W1,     // (E, A)
    const float* __restrict__ b1,     // (A)
    const float* __restrict__ W2,     // (A, 1)
    const float* __restrict__ b2,     // (1)
    float* __restrict__ out_vec,      // (B, E)
    float* __restrict__ out_attn)     // (B, NPAIR)
{
    __shared__ __align__(16) u16 xs[NF * XSTR];   // x, bf16, [field][e]
    __shared__ __align__(16) u16 Xt[EDIM * XSTR]; // x^T, bf16, [e][field]
    __shared__ __align__(16) u16 As[NF * XSTR];   // attn matrix, bf16, [i][j]
    __shared__ float logits[NPAIR];
    __shared__ unsigned short pairIJ[NPAIR];      // (i << 8) | j
    __shared__ float red[8];
    __shared__ float partial[4][EDIM];

    const int t    = threadIdx.x;
    const int b    = blockIdx.x;
    const int wid  = t >> 6;
    const int lane = t & 63;
    const int g    = lane >> 4;   // quarter-wave group
    const int m16  = lane & 15;

    // ---- stage x into LDS as bf16: row-major xs and transposed Xt ----
    const float4* xg4 = (const float4*)(emb + (size_t)b * NF * EDIM);
    for (int idx = t; idx < NF * EDIM / 4; idx += 256) {
        int f = idx >> 4, e4 = (idx & 15) * 4;
        float4 v = xg4[idx];
        u16 p0 = fb(v.x), p1 = fb(v.y), p2 = fb(v.z), p3 = fb(v.w);
        u16x4 pk = {p0, p1, p2, p3};
        *(u16x4*)&xs[f * XSTR + e4] = pk;
        Xt[(e4 + 0) * XSTR + f] = p0;
        Xt[(e4 + 1) * XSTR + f] = p1;
        Xt[(e4 + 2) * XSTR + f] = p2;
        Xt[(e4 + 3) * XSTR + f] = p3;
    }

    // ---- pair index table (np.triu_indices(64, k=1) order) ----
    for (int p = t; p < NPAIR; p += 256) {
        float fp = (float)p;
        int i = (int)((127.0f - sqrtf(16129.0f - 8.0f * fp)) * 0.5f);
        if (i < 0) i = 0;
        if (i > NF - 2) i = NF - 2;
        while (i < NF - 2 && (i + 1) * (2 * NF - i - 2) / 2 <= p) ++i;
        while (i > 0 && i * (2 * NF - i - 1) / 2 > p) --i;
        int j = p - i * (2 * NF - i - 1) / 2 + i + 1;
        pairIJ[p] = (unsigned short)((i << 8) | j);
    }

    // ---- W1^T fragments (A-operand) + per-lane bias/W2 slices ----
    bf16x8 w1f[2][2];
    #pragma unroll
    for (int kh = 0; kh < 2; ++kh)
        #pragma unroll
        for (int nh = 0; nh < 2; ++nh)
            #pragma unroll
            for (int j = 0; j < 8; ++j)
                w1f[kh][nh][j] =
                    (bf16_t)W1[(kh * 32 + 8 * g + j) * ADIM + nh * 16 + m16];

    float b1v[2][4], w2v[2][4];
    #pragma unroll
    for (int nh = 0; nh < 2; ++nh)
        #pragma unroll
        for (int r = 0; r < 4; ++r) {
            b1v[nh][r] = b1[nh * 16 + 4 * g + r];
            w2v[nh][r] = W2[nh * 16 + 4 * g + r];
        }
    const float b2s = b2[0];
    __syncthreads();

    // ---- phase 1: logits via MFMA, D = W1^T(32x64) @ inner^T(64x16) ----
    for (int tile = wid; tile < NTILE; tile += 4) {
        const int p  = tile * 16 + m16;
        const int ij = pairIJ[p];
        const u16* xi = &xs[(ij >> 8) * XSTR];
        const u16* xj = &xs[(ij & 255) * XSTR];

        // e-slices: kh=0 -> [8g, 8g+8), kh=1 -> [32+8g, 32+8g+8)
        bf16x8 xi0 = *(const bf16x8*)(xi + 8 * g);
        bf16x8 xi1 = *(const bf16x8*)(xi + 32 + 8 * g);
        bf16x8 xj0 = *(const bf16x8*)(xj + 8 * g);
        bf16x8 xj1 = *(const bf16x8*)(xj + 32 + 8 * g);

        bf16x8 bi0, bi1;
        #pragma unroll
        for (int j = 0; j < 8; ++j) {
            bi0[j] = (bf16_t)((float)xi0[j] * (float)xj0[j]);
            bi1[j] = (bf16_t)((float)xi1[j] * (float)xj1[j]);
        }

        f32x4 acc0 = {0.f, 0.f, 0.f, 0.f};
        f32x4 acc1 = {0.f, 0.f, 0.f, 0.f};
        acc0 = __builtin_amdgcn_mfma_f32_16x16x32_bf16(w1f[0][0], bi0, acc0, 0, 0, 0);
        acc1 = __builtin_amdgcn_mfma_f32_16x16x32_bf16(w1f[0][1], bi0, acc1, 0, 0, 0);
        acc0 = __builtin_amdgcn_mfma_f32_16x16x32_bf16(w1f[1][0], bi1, acc0, 0, 0, 0);
        acc1 = __builtin_amdgcn_mfma_f32_16x16x32_bf16(w1f[1][1], bi1, acc1, 0, 0, 0);

        float tr = 0.f;
        #pragma unroll
        for (int r = 0; r < 4; ++r) {
            tr += fmaxf(acc0[r] + b1v[0][r], 0.f) * w2v[0][r];
            tr += fmaxf(acc1[r] + b1v[1][r], 0.f) * w2v[1][r];
        }
        tr += __shfl_xor(tr, 16);
        tr += __shfl_xor(tr, 32);
        if (g == 0) logits[p] = tr + b2s;
    }
    __syncthreads();

    // ---- phase 2: softmax over 2016 pairs + build symmetric attn matrix ----
    float m = -INFINITY;
    for (int p = t; p < NPAIR; p += 256) m = fmaxf(m, logits[p]);
    #pragma unroll
    for (int off = 32; off; off >>= 1) m = fmaxf(m, __shfl_xor(m, off));
    if (lane == 0) red[wid] = m;
    __syncthreads();
    if (t == 0) red[4] = fmaxf(fmaxf(red[0], red[1]), fmaxf(red[2], red[3]));
    __syncthreads();
    m = red[4];

    float s = 0.0f;
    for (int p = t; p < NPAIR; p += 256) {
        float ev = __expf(logits[p] - m);
        logits[p] = ev;
        s += ev;
    }
    #pragma unroll
    for (int off = 32; off; off >>= 1) s += __shfl_xor(s, off);
    __syncthreads();
    if (lane == 0) red[wid] = s;
    __syncthreads();
    if (t == 0) red[5] = red[0] + red[1] + red[2] + red[3];
    __syncthreads();
    const float inv = 1.0f / red[5];

    for (int p = t; p < NPAIR; p += 256) {
        float av = logits[p] * inv;
        out_attn[(size_t)b * NPAIR + p] = av;
        u16 ab = fb(av);
        int ij = pairIJ[p];
        int i = ij >> 8, j = ij & 255;
        As[i * XSTR + j] = ab;
        As[j * XSTR + i] = ab;
    }
    if (t < NF) As[t * XSTR + t] = 0;
    __syncthreads();

    // ---- phase 3: Y = A @ X via MFMA; out[e] = 0.5 sum_i X[i,e] Y[i,e] ----
    const int itile = wid;          // each wave owns 16 rows of A
    f32x4 yacc[4];
    #pragma unroll
    for (int et = 0; et < 4; ++et) yacc[et] = (f32x4){0.f, 0.f, 0.f, 0.f};

    const u16* arow = &As[(itile * 16 + m16) * XSTR];
    bf16x8 af0 = *(const bf16x8*)(arow + 8 * g);          // k = 0..31 slice
    bf16x8 af1 = *(const bf16x8*)(arow + 32 + 8 * g);     // k = 32..63 slice
    #pragma unroll
    for (int et = 0; et < 4; ++et) {
        const u16* xtr = &Xt[(et * 16 + m16) * XSTR];
        bf16x8 bf0 = *(const bf16x8*)(xtr + 8 * g);
        bf16x8 bf1 = *(const bf16x8*)(xtr + 32 + 8 * g);
        yacc[et] = __builtin_amdgcn_mfma_f32_16x16x32_bf16(af0, bf0, yacc[et], 0, 0, 0);
        yacc[et] = __builtin_amdgcn_mfma_f32_16x16x32_bf16(af1, bf1, yacc[et], 0, 0, 0);
    }

    #pragma unroll
    for (int et = 0; et < 4; ++et) {
        float v = 0.f;
        #pragma unroll
        for (int r = 0; r < 4; ++r) {
            int i = itile * 16 + 4 * g + r;
            int e = et * 16 + m16;
            v = fmaf(bu(xs[i * XSTR + e]), yacc[et][r], v);
        }
        v += __shfl_xor(v, 16);
        v += __shfl_xor(v, 32);
        if (g == 0) partial[wid][et * 16 + m16] = v;
    }
    __syncthreads();
    if (t < EDIM)
        out_vec[(size_t)b * EDIM + t] = 0.5f *
            (partial[0][t] + partial[1][t] + partial[2][t] + partial[3][t]);
}

extern "C" void kernel_launch(void* const* d_in, const int* in_sizes, int n_in,
                              void* d_out, int out_size, void* d_ws, size_t ws_size,
                              hipStream_t stream) {
    const float* emb = (const float*)d_in[0];
    const float* W1  = (const float*)d_in[1];
    const float* b1  = (const float*)d_in[2];
    const float* W2  = (const float*)d_in[3];
    const float* b2  = (const float*)d_in[4];
    float* out_vec  = (float*)d_out;                        // (B, E)
    float* out_attn = (float*)d_out + (size_t)BATCH * EDIM; // (B, NPAIR)

    afm_kernel<<<BATCH, 256, 0, stream>>>(emb, W1, b1, W2, b2, out_vec, out_attn);
}

// Round 4
// 28.928 us; speedup vs baseline: 4.6075x; 1.4445x over previous
//
#include <hip/hip_runtime.h>

#define BATCH   1024
#define NF      64
#define EDIM    64
#define ADIM    32
#define NPAIR   2016        // 64*63/2
#define NTILE   126         // NPAIR / 16
#define XSTR    72          // f16 elems/row: 144B rows -> 16B aligned, bank rot 4/row

typedef _Float16 f16;
typedef f16   f16x4 __attribute__((ext_vector_type(4)));
typedef f16   f16x8 __attribute__((ext_vector_type(8)));
typedef float f32x4 __attribute__((ext_vector_type(4)));

__global__ __launch_bounds__(256) void afm_kernel(
    const float* __restrict__ emb,    // (B, NF, E)
    const float* __restrict__ W1,     // (E, A)
    const float* __restrict__ b1,     // (A)
    const float* __restrict__ W2,     // (A, 1)
    const float* __restrict__ b2,     // (1)
    float* __restrict__ out_vec,      // (B, E)
    float* __restrict__ out_attn)     // (B, NPAIR)
{
    __shared__ __align__(16) f16 xs[NF * XSTR];   // x, f16, [field][e]
    __shared__ __align__(16) f16 Xt[EDIM * XSTR]; // x^T, f16, [e][field]
    __shared__ __align__(16) f16 As[NF * XSTR];   // attn matrix, f16, [i][j]
    __shared__ float logits[NPAIR];
    __shared__ unsigned short pairIJ[NPAIR];      // (i << 8) | j
    __shared__ float red[8];
    __shared__ float partial[4][EDIM];

    const int t    = threadIdx.x;
    const int b    = blockIdx.x;
    const int wid  = t >> 6;
    const int lane = t & 63;
    const int g    = lane >> 4;   // quarter-wave group
    const int m16  = lane & 15;

    // ---- stage x into LDS as f16: row-major xs and transposed Xt ----
    const float4* xg4 = (const float4*)(emb + (size_t)b * NF * EDIM);
    #pragma unroll
    for (int it = 0; it < 4; ++it) {
        int idx = t + it * 256;
        int f = idx >> 4, e4 = (idx & 15) * 4;
        float4 v = xg4[idx];
        f16 h0 = (f16)v.x, h1 = (f16)v.y, h2 = (f16)v.z, h3 = (f16)v.w;
        f16x4 pk = {h0, h1, h2, h3};
        *(f16x4*)&xs[f * XSTR + e4] = pk;
        Xt[(e4 + 0) * XSTR + f] = h0;
        Xt[(e4 + 1) * XSTR + f] = h1;
        Xt[(e4 + 2) * XSTR + f] = h2;
        Xt[(e4 + 3) * XSTR + f] = h3;
    }

    // ---- pair index table, exact closed form ----
    // T(i) = i*(127-i)/2; boundaries satisfy 16129-8*T(i) = (127-2i)^2 exactly,
    // so sqrtf is exact there; interior margin >> fp32 sqrt error. Guard anyway.
    for (int p = t; p < NPAIR; p += 256) {
        int i = (int)(63.5f - 0.5f * sqrtf(16129.0f - 8.0f * (float)p));
        int Ti = (i * (127 - i)) >> 1;
        if (p < Ti)      { --i; Ti = (i * (127 - i)) >> 1; }
        else { int Tn = ((i + 1) * (126 - i)) >> 1; if (p >= Tn) { ++i; Ti = Tn; } }
        int j = p - Ti + i + 1;
        pairIJ[p] = (unsigned short)((i << 8) | j);
    }

    // ---- W1^T fragments (A-operand) + per-lane bias/W2 slices ----
    f16x8 w1f[2][2];
    #pragma unroll
    for (int kh = 0; kh < 2; ++kh)
        #pragma unroll
        for (int nh = 0; nh < 2; ++nh)
            #pragma unroll
            for (int j = 0; j < 8; ++j)
                w1f[kh][nh][j] =
                    (f16)W1[(kh * 32 + 8 * g + j) * ADIM + nh * 16 + m16];

    float b1v[2][4], w2v[2][4];
    #pragma unroll
    for (int nh = 0; nh < 2; ++nh)
        #pragma unroll
        for (int r = 0; r < 4; ++r) {
            b1v[nh][r] = b1[nh * 16 + 4 * g + r];
            w2v[nh][r] = W2[nh * 16 + 4 * g + r];
        }
    const float b2s = b2[0];
    __syncthreads();

    // ---- phase 1: logits via MFMA, D = W1^T(32x64) @ inner^T(64x16) ----
    // product fragment built with packed v_pk_mul_f16 (no unpack/repack).
    for (int tile = wid; tile < NTILE; tile += 4) {
        const int p  = tile * 16 + m16;
        const int ij = pairIJ[p];
        const f16* xi = &xs[(ij >> 8) * XSTR];
        const f16* xj = &xs[(ij & 255) * XSTR];

        f16x8 xi0 = *(const f16x8*)(xi + 8 * g);
        f16x8 xi1 = *(const f16x8*)(xi + 32 + 8 * g);
        f16x8 xj0 = *(const f16x8*)(xj + 8 * g);
        f16x8 xj1 = *(const f16x8*)(xj + 32 + 8 * g);
        f16x8 bi0 = xi0 * xj0;
        f16x8 bi1 = xi1 * xj1;

        f32x4 acc0 = {0.f, 0.f, 0.f, 0.f};
        f32x4 acc1 = {0.f, 0.f, 0.f, 0.f};
        acc0 = __builtin_amdgcn_mfma_f32_16x16x32_f16(w1f[0][0], bi0, acc0, 0, 0, 0);
        acc1 = __builtin_amdgcn_mfma_f32_16x16x32_f16(w1f[0][1], bi0, acc1, 0, 0, 0);
        acc0 = __builtin_amdgcn_mfma_f32_16x16x32_f16(w1f[1][0], bi1, acc0, 0, 0, 0);
        acc1 = __builtin_amdgcn_mfma_f32_16x16x32_f16(w1f[1][1], bi1, acc1, 0, 0, 0);

        float tr = 0.f;
        #pragma unroll
        for (int r = 0; r < 4; ++r) {
            tr += fmaxf(acc0[r] + b1v[0][r], 0.f) * w2v[0][r];
            tr += fmaxf(acc1[r] + b1v[1][r], 0.f) * w2v[1][r];
        }
        tr += __shfl_xor(tr, 16);
        tr += __shfl_xor(tr, 32);
        if (g == 0) logits[p] = tr + b2s;
    }
    __syncthreads();

    // ---- phase 2: softmax over 2016 pairs (logits cached in registers) ----
    float lv[8];
    #pragma unroll
    for (int k = 0; k < 8; ++k) {
        int p = t + 256 * k;
        lv[k] = (p < NPAIR) ? logits[p] : -INFINITY;
    }
    float m = lv[0];
    #pragma unroll
    for (int k = 1; k < 8; ++k) m = fmaxf(m, lv[k]);
    #pragma unroll
    for (int off = 32; off; off >>= 1) m = fmaxf(m, __shfl_xor(m, off));
    if (lane == 0) red[wid] = m;
    __syncthreads();
    if (t == 0) red[4] = fmaxf(fmaxf(red[0], red[1]), fmaxf(red[2], red[3]));
    __syncthreads();
    m = red[4];

    float s = 0.0f;
    #pragma unroll
    for (int k = 0; k < 8; ++k) {
        float ev = __expf(lv[k] - m);   // exp(-inf) = 0 for padded slots
        lv[k] = ev;
        s += ev;
    }
    #pragma unroll
    for (int off = 32; off; off >>= 1) s += __shfl_xor(s, off);
    __syncthreads();               // red[4] reads done before overwrite
    if (lane == 0) red[wid] = s;
    __syncthreads();
    if (t == 0) red[5] = red[0] + red[1] + red[2] + red[3];
    __syncthreads();
    const float inv = 1.0f / red[5];

    // attn write-out + symmetric attn matrix build
    #pragma unroll
    for (int k = 0; k < 8; ++k) {
        int p = t + 256 * k;
        if (p < NPAIR) {
            float av = lv[k] * inv;
            out_attn[(size_t)b * NPAIR + p] = av;
            f16 ah = (f16)av;
            int ij = pairIJ[p];
            int i = ij >> 8, j = ij & 255;
            As[i * XSTR + j] = ah;
            As[j * XSTR + i] = ah;
        }
    }
    if (t < NF) As[t * XSTR + t] = (f16)0.f;
    __syncthreads();

    // ---- phase 3: Y = A @ X via MFMA; out[e] = 0.5 sum_i X[i,e] Y[i,e] ----
    const int itile = wid;          // each wave owns 16 rows of A
    f32x4 yacc[4];
    #pragma unroll
    for (int et = 0; et < 4; ++et) yacc[et] = (f32x4){0.f, 0.f, 0.f, 0.f};

    const f16* arow = &As[(itile * 16 + m16) * XSTR];
    f16x8 af0 = *(const f16x8*)(arow + 8 * g);          // k = 0..31 slice
    f16x8 af1 = *(const f16x8*)(arow + 32 + 8 * g);     // k = 32..63 slice
    #pragma unroll
    for (int et = 0; et < 4; ++et) {
        const f16* xtr = &Xt[(et * 16 + m16) * XSTR];
        f16x8 bf0 = *(const f16x8*)(xtr + 8 * g);
        f16x8 bf1 = *(const f16x8*)(xtr + 32 + 8 * g);
        yacc[et] = __builtin_amdgcn_mfma_f32_16x16x32_f16(af0, bf0, yacc[et], 0, 0, 0);
        yacc[et] = __builtin_amdgcn_mfma_f32_16x16x32_f16(af1, bf1, yacc[et], 0, 0, 0);
    }

    #pragma unroll
    for (int et = 0; et < 4; ++et) {
        float v = 0.f;
        #pragma unroll
        for (int r = 0; r < 4; ++r) {
            int i = itile * 16 + 4 * g + r;
            int e = et * 16 + m16;
            v = fmaf((float)xs[i * XSTR + e], yacc[et][r], v);
        }
        v += __shfl_xor(v, 16);
        v += __shfl_xor(v, 32);
        if (g == 0) partial[wid][et * 16 + m16] = v;
    }
    __syncthreads();
    if (t < EDIM)
        out_vec[(size_t)b * EDIM + t] = 0.5f *
            (partial[0][t] + partial[1][t] + partial[2][t] + partial[3][t]);
}

extern "C" void kernel_launch(void* const* d_in, const int* in_sizes, int n_in,
                              void* d_out, int out_size, void* d_ws, size_t ws_size,
                              hipStream_t stream) {
    const float* emb = (const float*)d_in[0];
    const float* W1  = (const float*)d_in[1];
    const float* b1  = (const float*)d_in[2];
    const float* W2  = (const float*)d_in[3];
    const float* b2  = (const float*)d_in[4];
    float* out_vec  = (float*)d_out;                        // (B, E)
    float* out_attn = (float*)d_out + (size_t)BATCH * EDIM; // (B, NPAIR)

    afm_kernel<<<BATCH, 256, 0, stream>>>(emb, W1, b1, W2, b2, out_vec, out_attn);
}

// Round 6
// 26.476 us; speedup vs baseline: 5.0343x; 1.0926x over previous
//
#include <hip/hip_runtime.h>

#define BATCH   1024
#define NF      64
#define EDIM    64
#define ADIM    32
#define NPAIR   2016        // 64*63/2
#define XSTR    72          // f16 elems/row: 144B rows -> 16B aligned, bank rot 4/row

typedef _Float16 f16;
typedef f16   f16x4  __attribute__((ext_vector_type(4)));
typedef f16   f16x8  __attribute__((ext_vector_type(8)));
typedef float f32x4  __attribute__((ext_vector_type(4)));
typedef float f32x16 __attribute__((ext_vector_type(16)));

__device__ __forceinline__ f16x8 asH(int4 v) {
    union { int4 i; f16x8 h; } u; u.i = v; return u.h;
}

__global__ __launch_bounds__(256, 4) void afm_kernel(
    const float* __restrict__ emb,    // (B, NF, E)
    const float* __restrict__ W1,     // (E, A)
    const float* __restrict__ b1,     // (A)
    const float* __restrict__ W2,     // (A, 1)
    const float* __restrict__ b2,     // (1)
    float* __restrict__ out_vec,      // (B, E)
    float* __restrict__ out_attn)     // (B, NPAIR)
{
    __shared__ __align__(16) f16 xs[NF * XSTR];   // x, f16, [field][e]
    __shared__ __align__(16) f16 Xt[EDIM * XSTR]; // x^T, f16, [e][field]
    __shared__ __align__(16) f16 As[NF * XSTR];   // attn matrix, f16, [i][j]
    __shared__ float logits[NPAIR];
    __shared__ float red[8];
    __shared__ float partial[4][EDIM];

    const int t    = threadIdx.x;
    const int b    = blockIdx.x;
    const int wid  = t >> 6;
    const int lane = t & 63;
    const int g    = lane >> 4;   // for phase 3 (16x16 fragments)
    const int m16  = lane & 15;
    const int h    = lane >> 5;   // K-half for 32x32 fragments
    const int l32  = lane & 31;
    const int l16  = lane & 15;
    const int hb   = l32 >> 4;    // 16-row within 32-col group

    // ---- stage x into LDS as f16 (row-major; transpose built later) ----
    const float4* xg4 = (const float4*)(emb + (size_t)b * NF * EDIM);
    #pragma unroll
    for (int it = 0; it < 4; ++it) {
        int idx = t + it * 256;
        int f = idx >> 4, e4 = (idx & 15) * 4;
        float4 v = xg4[idx];
        f16x4 pk = {(f16)v.x, (f16)v.y, (f16)v.z, (f16)v.w};
        *(f16x4*)&xs[f * XSTR + e4] = pk;
    }

    // ---- W1^T A-fragments for 32x32x16: A[m=adim=l32][k=8h+jj] ----
    f16x8 w1a[4];
    #pragma unroll
    for (int q = 0; q < 4; ++q)
        #pragma unroll
        for (int jj = 0; jj < 8; ++jj)
            w1a[q][jj] = (f16)W1[(16 * q + 8 * h + jj) * ADIM + l32];

    // per-lane b1/W2 slices in C/D row order: a = (r&3) + 8*(r>>2) + 4*h
    float b1v[16], w2v[16];
    #pragma unroll
    for (int r = 0; r < 16; ++r) {
        int a = (r & 3) + 8 * (r >> 2) + 4 * h;
        b1v[r] = b1[a];
        w2v[r] = W2[a];
    }
    const float b2s = b2[0];
    __syncthreads();

    // ---- build Xt via read-transpose (conflict-free both sides) ----
    {
        const unsigned short* xsu = (const unsigned short*)xs;
        #pragma unroll
        for (int it = 0; it < 2; ++it) {
            int cid = t + it * 256;
            int e = cid & 63, c = cid >> 6;     // e = lane, c uniform per wave
            unsigned int d[4];
            #pragma unroll
            for (int r2 = 0; r2 < 4; ++r2) {
                unsigned lo = xsu[(8 * c + 2 * r2)     * XSTR + e];
                unsigned hi = xsu[(8 * c + 2 * r2 + 1) * XSTR + e];
                d[r2] = lo | (hi << 16);
            }
            int4 w4 = {(int)d[0], (int)d[1], (int)d[2], (int)d[3]};
            *(int4*)&Xt[e * XSTR + 8 * c] = w4;
        }
    }
    __syncthreads();

    // ---- DPP direction probe: row_ror:4 is either step +4 or -4 over l16 ----
    // jv registers are rotated WITH the data, so pair claims are always
    // consistent; only the diag-ring start offset needs the direction.
    int probe = __builtin_amdgcn_mov_dpp(l16, 0x124, 0xF, 0xF, false);
    const bool plus4 = (probe == ((l16 + 4) & 15));
    const int  s0r   = plus4 ? (wid + 1) : (wid + 5);  // ring steps = {s0r, s0r+/-4} = {1..8}

    // ---- phase 1: logits via 32x32x16 MFMA, register rows + DPP rotation ----
    int4 xi4[4], xj4[4];

    auto LOADX = [&](int row, int4* d) {
        #pragma unroll
        for (int q = 0; q < 4; ++q)
            d[q] = *(const int4*)&xs[row * XSTR + 16 * q + 8 * h];
    };
    auto ROT4D = [&](int4* d, int& jv) {   // rotate data AND its row index
        #pragma unroll
        for (int q = 0; q < 4; ++q) {
            d[q].x = __builtin_amdgcn_mov_dpp(d[q].x, 0x124, 0xF, 0xF, false);
            d[q].y = __builtin_amdgcn_mov_dpp(d[q].y, 0x124, 0xF, 0xF, false);
            d[q].z = __builtin_amdgcn_mov_dpp(d[q].z, 0x124, 0xF, 0xF, false);
            d[q].w = __builtin_amdgcn_mov_dpp(d[q].w, 0x124, 0xF, 0xF, false);
        }
        jv = __builtin_amdgcn_mov_dpp(jv, 0x124, 0xF, 0xF, false);
    };
    auto SUB = [&](const int4* xa, const int4* xb, int iv, int jv) {
        f32x16 acc = {};
        #pragma unroll
        for (int q = 0; q < 4; ++q) {
            f16x8 prod = asH(xa[q]) * asH(xb[q]);   // v_pk_mul_f16 x4
            acc = __builtin_amdgcn_mfma_f32_32x32x16_f16(w1a[q], prod, acc, 0, 0, 0);
        }
        float t0 = 0.f, t1 = 0.f;
        #pragma unroll
        for (int r = 0; r < 16; r += 2) {
            t0 += fmaxf(acc[r]     + b1v[r],     0.f) * w2v[r];
            t1 += fmaxf(acc[r + 1] + b1v[r + 1], 0.f) * w2v[r + 1];
        }
        float tr = t0 + t1;
        tr += __shfl_xor(tr, 32);
        int imin = min(iv, jv), jmax = max(iv, jv);
        int p = ((imin * (127 - imin)) >> 1) + jmax - imin - 1;
        if (lane < 32) logits[p] = tr + b2s;
    };

    // run 1: I=[0,32) rows in xi (shared by off-diag and ring(0,0))
    LOADX(l32, xi4);
    {   // off-diag (0,1) pattern A: 16 offsets covered as coset {wid +/- 4k}
        int jv = 32 + 16 * hb + ((l16 + wid) & 15);
        LOADX(jv, xj4);
        #pragma unroll
        for (int k = 0; k < 4; ++k) {
            SUB(xi4, xj4, l32, jv);
            if (k < 3) ROT4D(xj4, jv);
        }
    }
    {   // off-diag (0,1) pattern B: the other 16-block
        int jv = 32 + 16 * (1 - hb) + ((l16 + wid) & 15);
        LOADX(jv, xj4);
        #pragma unroll
        for (int k = 0; k < 4; ++k) {
            SUB(xi4, xj4, l32, jv);
            if (k < 3) ROT4D(xj4, jv);
        }
    }
    {   // diag (0,0) ring: steps {s0r, s0r+/-4} = s in {1..8} across waves
        int jv = 16 * hb + ((l16 + s0r) & 15);
        LOADX(jv, xj4);
        SUB(xi4, xj4, l32, jv);
        ROT4D(xj4, jv);
        SUB(xi4, xj4, l32, jv);
    }
    {   // diag (0,0) cross: i in [0,16), j in [16,32); {wid,wid+/-4}+8hb covers 0..15
        int jv = 16 + ((l16 + wid + 8 * hb) & 15);
        LOADX(l16, xi4);
        LOADX(jv, xj4);
        SUB(xi4, xj4, l16, jv);
        ROT4D(xj4, jv);
        SUB(xi4, xj4, l16, jv);
    }
    {   // diag (1,1) ring
        int jv = 32 + 16 * hb + ((l16 + s0r) & 15);
        LOADX(32 + l32, xi4);
        LOADX(jv, xj4);
        SUB(xi4, xj4, 32 + l32, jv);
        ROT4D(xj4, jv);
        SUB(xi4, xj4, 32 + l32, jv);
    }
    {   // diag (1,1) cross
        int jv = 48 + ((l16 + wid + 8 * hb) & 15);
        LOADX(32 + l16, xi4);
        LOADX(jv, xj4);
        SUB(xi4, xj4, 32 + l16, jv);
        ROT4D(xj4, jv);
        SUB(xi4, xj4, 32 + l16, jv);
    }
    __syncthreads();

    // ---- phase 2: softmax over 2016 pairs (logits cached in registers) ----
    float lv[8];
    #pragma unroll
    for (int k = 0; k < 8; ++k) {
        int p = t + 256 * k;
        lv[k] = (p < NPAIR) ? logits[p] : -INFINITY;
    }
    float m = lv[0];
    #pragma unroll
    for (int k = 1; k < 8; ++k) m = fmaxf(m, lv[k]);
    #pragma unroll
    for (int off = 32; off; off >>= 1) m = fmaxf(m, __shfl_xor(m, off));
    if (lane == 0) red[wid] = m;
    __syncthreads();
    if (t == 0) red[4] = fmaxf(fmaxf(red[0], red[1]), fmaxf(red[2], red[3]));
    __syncthreads();
    m = red[4];

    float s = 0.0f;
    #pragma unroll
    for (int k = 0; k < 8; ++k) {
        float ev = __expf(lv[k] - m);
        lv[k] = ev;
        s += ev;
    }
    #pragma unroll
    for (int off = 32; off; off >>= 1) s += __shfl_xor(s, off);
    __syncthreads();
    if (lane == 0) red[wid] = s;
    __syncthreads();
    if (t == 0) red[5] = red[0] + red[1] + red[2] + red[3];
    __syncthreads();
    const float inv = 1.0f / red[5];

    // attn write-out + symmetric attn matrix build (closed-form (i,j) from p)
    #pragma unroll
    for (int k = 0; k < 8; ++k) {
        int p = t + 256 * k;
        if (p < NPAIR) {
            float av = lv[k] * inv;
            out_attn[(size_t)b * NPAIR + p] = av;
            int i = (int)(63.5f - 0.5f * sqrtf(16129.0f - 8.0f * (float)p));
            int Ti = (i * (127 - i)) >> 1;
            if (p < Ti)      { --i; Ti = (i * (127 - i)) >> 1; }
            else { int Tn = ((i + 1) * (126 - i)) >> 1; if (p >= Tn) { ++i; Ti = Tn; } }
            int j = p - Ti + i + 1;
            f16 ah = (f16)av;
            As[i * XSTR + j] = ah;
            As[j * XSTR + i] = ah;
        }
    }
    if (t < NF) As[t * XSTR + t] = (f16)0.f;
    __syncthreads();

    // ---- phase 3: Y = A @ X via MFMA; out[e] = 0.5 sum_i X[i,e] Y[i,e] ----
    const int itile = wid;          // each wave owns 16 rows of A
    f32x4 yacc[4];
    #pragma unroll
    for (int et = 0; et < 4; ++et) yacc[et] = (f32x4){0.f, 0.f, 0.f, 0.f};

    const f16* arow = &As[(itile * 16 + m16) * XSTR];
    f16x8 af0 = *(const f16x8*)(arow + 8 * g);          // k = 0..31 slice
    f16x8 af1 = *(const f16x8*)(arow + 32 + 8 * g);     // k = 32..63 slice
    #pragma unroll
    for (int et = 0; et < 4; ++et) {
        const f16* xtr = &Xt[(et * 16 + m16) * XSTR];
        f16x8 bf0 = *(const f16x8*)(xtr + 8 * g);
        f16x8 bf1 = *(const f16x8*)(xtr + 32 + 8 * g);
        yacc[et] = __builtin_amdgcn_mfma_f32_16x16x32_f16(af0, bf0, yacc[et], 0, 0, 0);
        yacc[et] = __builtin_amdgcn_mfma_f32_16x16x32_f16(af1, bf1, yacc[et], 0, 0, 0);
    }

    #pragma unroll
    for (int et = 0; et < 4; ++et) {
        float v = 0.f;
        #pragma unroll
        for (int r = 0; r < 4; ++r) {
            int i = itile * 16 + 4 * g + r;
            int e = et * 16 + m16;
            v = fmaf((float)xs[i * XSTR + e], yacc[et][r], v);
        }
        v += __shfl_xor(v, 16);
        v += __shfl_xor(v, 32);
        if (g == 0) partial[wid][et * 16 + m16] = v;
    }
    __syncthreads();
    if (t < EDIM)
        out_vec[(size_t)b * EDIM + t] = 0.5f *
            (partial[0][t] + partial[1][t] + partial[2][t] + partial[3][t]);
}

extern "C" void kernel_launch(void* const* d_in, const int* in_sizes, int n_in,
                              void* d_out, int out_size, void* d_ws, size_t ws_size,
                              hipStream_t stream) {
    const float* emb = (const float*)d_in[0];
    const float* W1  = (const float*)d_in[1];
    const float* b1  = (const float*)d_in[2];
    const float* W2  = (const float*)d_in[3];
    const float* b2  = (const float*)d_in[4];
    float* out_vec  = (float*)d_out;                        // (B, E)
    float* out_attn = (float*)d_out + (size_t)BATCH * EDIM; // (B, NPAIR)

    afm_kernel<<<BATCH, 256, 0, stream>>>(emb, W1, b1, W2, b2, out_vec, out_attn);
}

// Round 7
// 26.276 us; speedup vs baseline: 5.0726x; 1.0076x over previous
//
#include <hip/hip_runtime.h>

#define BATCH   1024
#define NF      64
#define EDIM    64
#define ADIM    32
#define NPAIR   2016        // 64*63/2
#define XSTR    72          // f16 elems/row: 144B rows -> 16B aligned, bank rot 4/row
#define ASTR    68          // As stride: 136B rows -> 8B aligned (b64 reads), 4-way col scatter

typedef _Float16 f16;
typedef f16   f16x4  __attribute__((ext_vector_type(4)));
typedef f16   f16x8  __attribute__((ext_vector_type(8)));
typedef float f32x2  __attribute__((ext_vector_type(2)));
typedef float f32x4  __attribute__((ext_vector_type(4)));
typedef float f32x16 __attribute__((ext_vector_type(16)));

__device__ __forceinline__ f16x8 asH(int4 v) {
    union { int4 i; f16x8 h; } u; u.i = v; return u.h;
}

__global__ __launch_bounds__(256, 4) void afm_kernel(
    const float* __restrict__ emb,    // (B, NF, E)
    const float* __restrict__ W1,     // (E, A)
    const float* __restrict__ b1,     // (A)
    const float* __restrict__ W2,     // (A, 1)
    const float* __restrict__ b2,     // (1)
    float* __restrict__ out_vec,      // (B, E)
    float* __restrict__ out_attn)     // (B, NPAIR)
{
    __shared__ __align__(16) f16 xs[NF * XSTR];   // x, f16, [field][e]
    __shared__ __align__(16) f16 Xt[EDIM * XSTR]; // x^T, f16, [e][field]
    // Overlay region: logits [0,8064) + partial [8064,9088); As f16 stride 68
    // aliases [0,8704). Safe: As written only after all logits reads (lv regs),
    // partial written only after a barrier following the last As read.
    __shared__ __align__(16) char Ubuf[9088];
    float* logits = (float*)Ubuf;
    float (*partial)[EDIM] = (float (*)[EDIM])(Ubuf + 8064);
    f16* As = (f16*)Ubuf;
    __shared__ float red[8];

    const int t    = threadIdx.x;
    const int b    = blockIdx.x;
    const int wid  = t >> 6;
    const int lane = t & 63;
    const int g    = lane >> 4;   // for phase 3 (16x16 fragments)
    const int m16  = lane & 15;
    const int h    = lane >> 5;   // K-half for 32x32 fragments
    const int l32  = lane & 31;
    const int l16  = lane & 15;
    const int hb   = l32 >> 4;    // 16-row within 32-col group

    // ---- stage x into LDS as f16 (row-major; transpose built later) ----
    const float4* xg4 = (const float4*)(emb + (size_t)b * NF * EDIM);
    #pragma unroll
    for (int it = 0; it < 4; ++it) {
        int idx = t + it * 256;
        int f = idx >> 4, e4 = (idx & 15) * 4;
        float4 v = xg4[idx];
        f16x4 pk = {(f16)v.x, (f16)v.y, (f16)v.z, (f16)v.w};
        *(f16x4*)&xs[f * XSTR + e4] = pk;
    }

    // ---- W1^T A-fragments for 32x32x16: A[m=adim=l32][k=8h+jj] ----
    f16x8 w1a[4];
    #pragma unroll
    for (int q = 0; q < 4; ++q)
        #pragma unroll
        for (int jj = 0; jj < 8; ++jj)
            w1a[q][jj] = (f16)W1[(16 * q + 8 * h + jj) * ADIM + l32];

    // b1/W2 as packed f32x2 pairs in C/D row order: a(r) = (r&3)+8*(r>>2)+4h;
    // for even r, a(r+1) = a(r)+1, so pairs are contiguous.
    f32x2 b1f2[8], w2f2[8];
    #pragma unroll
    for (int rr = 0; rr < 8; ++rr) {
        int r = 2 * rr;
        int a = (r & 3) + 8 * (r >> 2) + 4 * h;
        b1f2[rr] = (f32x2){b1[a], b1[a + 1]};
        w2f2[rr] = (f32x2){W2[a], W2[a + 1]};
    }
    const float b2s = b2[0];
    __syncthreads();

    // ---- build Xt via read-transpose (conflict-free both sides) ----
    {
        const unsigned short* xsu = (const unsigned short*)xs;
        #pragma unroll
        for (int it = 0; it < 2; ++it) {
            int cid = t + it * 256;
            int e = cid & 63, c = cid >> 6;     // e = lane, c uniform per wave
            unsigned int d[4];
            #pragma unroll
            for (int r2 = 0; r2 < 4; ++r2) {
                unsigned lo = xsu[(8 * c + 2 * r2)     * XSTR + e];
                unsigned hi = xsu[(8 * c + 2 * r2 + 1) * XSTR + e];
                d[r2] = lo | (hi << 16);
            }
            int4 w4 = {(int)d[0], (int)d[1], (int)d[2], (int)d[3]};
            *(int4*)&Xt[e * XSTR + 8 * c] = w4;
        }
    }
    __syncthreads();

    // ---- DPP direction probe (see round-6 notes): jv rotates WITH data ----
    int probe = __builtin_amdgcn_mov_dpp(l16, 0x124, 0xF, 0xF, false);
    const bool plus4 = (probe == ((l16 + 4) & 15));
    const int  s0r   = plus4 ? (wid + 1) : (wid + 5);

    // ---- phase 1: logits via 32x32x16 MFMA, register rows + DPP rotation ----
    int4 xi4[4], xj4[4];

    auto LOADX = [&](int row, int4* d) {
        #pragma unroll
        for (int q = 0; q < 4; ++q)
            d[q] = *(const int4*)&xs[row * XSTR + 16 * q + 8 * h];
    };
    auto ROT4D = [&](int4* d, int& jv) {   // rotate data AND its row index
        #pragma unroll
        for (int q = 0; q < 4; ++q) {
            d[q].x = __builtin_amdgcn_mov_dpp(d[q].x, 0x124, 0xF, 0xF, false);
            d[q].y = __builtin_amdgcn_mov_dpp(d[q].y, 0x124, 0xF, 0xF, false);
            d[q].z = __builtin_amdgcn_mov_dpp(d[q].z, 0x124, 0xF, 0xF, false);
            d[q].w = __builtin_amdgcn_mov_dpp(d[q].w, 0x124, 0xF, 0xF, false);
        }
        jv = __builtin_amdgcn_mov_dpp(jv, 0x124, 0xF, 0xF, false);
    };
    auto SUB = [&](const int4* xa, const int4* xb, int iv, int jv) {
        f32x16 acc = {};
        #pragma unroll
        for (int q = 0; q < 4; ++q) {
            f16x8 prod = asH(xa[q]) * asH(xb[q]);   // v_pk_mul_f16 x4
            acc = __builtin_amdgcn_mfma_f32_32x32x16_f16(w1a[q], prod, acc, 0, 0, 0);
        }
        // packed-f32 epilogue: v_pk_add/max/fma_f32 candidates
        f32x2 tr2 = {0.f, 0.f};
        #pragma unroll
        for (int rr = 0; rr < 8; ++rr) {
            f32x2 a2 = {acc[2 * rr], acc[2 * rr + 1]};
            f32x2 h2 = __builtin_elementwise_max(a2 + b1f2[rr], (f32x2){0.f, 0.f});
            tr2 += h2 * w2f2[rr];
        }
        float tr = tr2.x + tr2.y;
        tr += __shfl_xor(tr, 32);
        int imin = min(iv, jv), jmax = max(iv, jv);
        int p = ((imin * (127 - imin)) >> 1) + jmax - imin - 1;
        if (lane < 32) logits[p] = tr + b2s;
    };

    LOADX(l32, xi4);
    {   // off-diag (0,1) pattern A
        int jv = 32 + 16 * hb + ((l16 + wid) & 15);
        LOADX(jv, xj4);
        #pragma unroll
        for (int k = 0; k < 4; ++k) {
            SUB(xi4, xj4, l32, jv);
            if (k < 3) ROT4D(xj4, jv);
        }
    }
    {   // off-diag (0,1) pattern B
        int jv = 32 + 16 * (1 - hb) + ((l16 + wid) & 15);
        LOADX(jv, xj4);
        #pragma unroll
        for (int k = 0; k < 4; ++k) {
            SUB(xi4, xj4, l32, jv);
            if (k < 3) ROT4D(xj4, jv);
        }
    }
    {   // diag (0,0) ring
        int jv = 16 * hb + ((l16 + s0r) & 15);
        LOADX(jv, xj4);
        SUB(xi4, xj4, l32, jv);
        ROT4D(xj4, jv);
        SUB(xi4, xj4, l32, jv);
    }
    {   // diag (0,0) cross
        int jv = 16 + ((l16 + wid + 8 * hb) & 15);
        LOADX(l16, xi4);
        LOADX(jv, xj4);
        SUB(xi4, xj4, l16, jv);
        ROT4D(xj4, jv);
        SUB(xi4, xj4, l16, jv);
    }
    {   // diag (1,1) ring
        int jv = 32 + 16 * hb + ((l16 + s0r) & 15);
        LOADX(32 + l32, xi4);
        LOADX(jv, xj4);
        SUB(xi4, xj4, 32 + l32, jv);
        ROT4D(xj4, jv);
        SUB(xi4, xj4, 32 + l32, jv);
    }
    {   // diag (1,1) cross
        int jv = 48 + ((l16 + wid + 8 * hb) & 15);
        LOADX(32 + l16, xi4);
        LOADX(jv, xj4);
        SUB(xi4, xj4, 32 + l16, jv);
        ROT4D(xj4, jv);
        SUB(xi4, xj4, 32 + l16, jv);
    }
    __syncthreads();

    // ---- phase 2: one-hop online softmax over 2016 pairs ----
    float lv[8];
    #pragma unroll
    for (int k = 0; k < 8; ++k) {
        int p = t + 256 * k;
        lv[k] = (p < NPAIR) ? logits[p] : -INFINITY;
    }
    float mw = lv[0];
    #pragma unroll
    for (int k = 1; k < 8; ++k) mw = fmaxf(mw, lv[k]);
    #pragma unroll
    for (int off = 32; off; off >>= 1) mw = fmaxf(mw, __shfl_xor(mw, off));

    float sw = 0.0f;
    #pragma unroll
    for (int k = 0; k < 8; ++k) {
        float ev = __expf(lv[k] - mw);   // exp(-inf) = 0 for padded slots
        lv[k] = ev;
        sw += ev;
    }
    #pragma unroll
    for (int off = 32; off; off >>= 1) sw += __shfl_xor(sw, off);
    if (lane == 0) { red[wid] = mw; red[4 + wid] = sw; }
    __syncthreads();
    const float mg = fmaxf(fmaxf(red[0], red[1]), fmaxf(red[2], red[3]));
    const float ssum = red[4] * __expf(red[0] - mg) + red[5] * __expf(red[1] - mg)
                     + red[6] * __expf(red[2] - mg) + red[7] * __expf(red[3] - mg);
    const float fsc = __expf(mw - mg) / ssum;   // wave-uniform rescale * 1/sum

    // attn write-out + symmetric attn matrix build (closed-form (i,j) from p)
    #pragma unroll
    for (int k = 0; k < 8; ++k) {
        int p = t + 256 * k;
        if (p < NPAIR) {
            float av = lv[k] * fsc;
            out_attn[(size_t)b * NPAIR + p] = av;
            int i = (int)(63.5f - 0.5f * sqrtf(16129.0f - 8.0f * (float)p));
            int Ti = (i * (127 - i)) >> 1;
            if (p < Ti)      { --i; Ti = (i * (127 - i)) >> 1; }
            else { int Tn = ((i + 1) * (126 - i)) >> 1; if (p >= Tn) { ++i; Ti = Tn; } }
            int j = p - Ti + i + 1;
            f16 ah = (f16)av;
            As[i * ASTR + j] = ah;
            As[j * ASTR + i] = ah;
        }
    }
    if (t < NF) As[t * ASTR + t] = (f16)0.f;
    __syncthreads();

    // ---- phase 3: Y = A @ X via MFMA; out[e] = 0.5 sum_i X[i,e] Y[i,e] ----
    const int itile = wid;          // each wave owns 16 rows of A
    // load A-fragments first (the only As reads), then barrier before any
    // partial[] write (partial aliases As).
    const f16* arow = &As[(itile * 16 + m16) * ASTR];
    f16x4 afa0 = *(const f16x4*)(arow + 8 * g);
    f16x4 afb0 = *(const f16x4*)(arow + 8 * g + 4);
    f16x4 afa1 = *(const f16x4*)(arow + 32 + 8 * g);
    f16x4 afb1 = *(const f16x4*)(arow + 32 + 8 * g + 4);
    __syncthreads();
    f16x8 af0, af1;
    #pragma unroll
    for (int j = 0; j < 4; ++j) {
        af0[j] = afa0[j]; af0[4 + j] = afb0[j];
        af1[j] = afa1[j]; af1[4 + j] = afb1[j];
    }

    f32x4 yacc[4];
    #pragma unroll
    for (int et = 0; et < 4; ++et) yacc[et] = (f32x4){0.f, 0.f, 0.f, 0.f};
    #pragma unroll
    for (int et = 0; et < 4; ++et) {
        const f16* xtr = &Xt[(et * 16 + m16) * XSTR];
        f16x8 bf0 = *(const f16x8*)(xtr + 8 * g);
        f16x8 bf1 = *(const f16x8*)(xtr + 32 + 8 * g);
        yacc[et] = __builtin_amdgcn_mfma_f32_16x16x32_f16(af0, bf0, yacc[et], 0, 0, 0);
        yacc[et] = __builtin_amdgcn_mfma_f32_16x16x32_f16(af1, bf1, yacc[et], 0, 0, 0);
    }

    #pragma unroll
    for (int et = 0; et < 4; ++et) {
        float v = 0.f;
        #pragma unroll
        for (int r = 0; r < 4; ++r) {
            int i = itile * 16 + 4 * g + r;
            int e = et * 16 + m16;
            v = fmaf((float)xs[i * XSTR + e], yacc[et][r], v);
        }
        v += __shfl_xor(v, 16);
        v += __shfl_xor(v, 32);
        if (g == 0) partial[wid][et * 16 + m16] = v;
    }
    __syncthreads();
    if (t < EDIM)
        out_vec[(size_t)b * EDIM + t] = 0.5f *
            (partial[0][t] + partial[1][t] + partial[2][t] + partial[3][t]);
}

extern "C" void kernel_launch(void* const* d_in, const int* in_sizes, int n_in,
                              void* d_out, int out_size, void* d_ws, size_t ws_size,
                              hipStream_t stream) {
    const float* emb = (const float*)d_in[0];
    const float* W1  = (const float*)d_in[1];
    const float* b1  = (const float*)d_in[2];
    const float* W2  = (const float*)d_in[3];
    const float* b2  = (const float*)d_in[4];
    float* out_vec  = (float*)d_out;                        // (B, E)
    float* out_attn = (float*)d_out + (size_t)BATCH * EDIM; // (B, NPAIR)

    afm_kernel<<<BATCH, 256, 0, stream>>>(emb, W1, b1, W2, b2, out_vec, out_attn);
}

// Round 9
// 24.211 us; speedup vs baseline: 5.5052x; 1.0853x over previous
//
#include <hip/hip_runtime.h>

#define BATCH   1024
#define NF      64
#define EDIM    64
#define ADIM    32
#define NPAIR   2016        // 64*63/2
#define XSTR    72          // f16 elems/row: 144B rows -> 16B aligned, bank rot 4/row
#define ASTR    68          // As stride: 136B rows -> 8B aligned (b64 reads), 4-way col scatter

typedef _Float16 f16;
typedef f16   f16x2  __attribute__((ext_vector_type(2)));
typedef f16   f16x4  __attribute__((ext_vector_type(4)));
typedef f16   f16x8  __attribute__((ext_vector_type(8)));
typedef float f32x2  __attribute__((ext_vector_type(2)));
typedef float f32x4  __attribute__((ext_vector_type(4)));
typedef float f32x16 __attribute__((ext_vector_type(16)));

__device__ __forceinline__ f16x8 asH(int4 v) {
    union { int4 i; f16x8 h; } u; u.i = v; return u.h;
}
__device__ __forceinline__ f16x2 pkrtz(float a, float b) {
    union { __fp16 __attribute__((ext_vector_type(2))) r; f16x2 h; } u;
    u.r = __builtin_amdgcn_cvt_pkrtz(a, b);
    return u.h;
}

__global__ __launch_bounds__(256, 4) void afm_kernel(
    const float* __restrict__ emb,    // (B, NF, E)
    const float* __restrict__ W1,     // (E, A)
    const float* __restrict__ b1,     // (A)
    const float* __restrict__ W2,     // (A, 1)
    const float* __restrict__ b2,     // (1)
    float* __restrict__ out_vec,      // (B, E)
    float* __restrict__ out_attn)     // (B, NPAIR)
{
    __shared__ __align__(16) f16 xs[NF * XSTR];   // x, f16, [field][e]
    __shared__ __align__(16) f16 Xt[EDIM * XSTR]; // x^T, f16, [e][field]
    __shared__ __align__(16) f16 As[NF * ASTR];   // UNNORMALIZED exp matrix, f16
    __shared__ float logits[NPAIR];               // unnormalized exp values, f32
    __shared__ float partial[4][EDIM];
    __shared__ float red[8];

    const int t    = threadIdx.x;
    const int b    = blockIdx.x;
    const int wid  = t >> 6;
    const int lane = t & 63;
    const int g    = lane >> 4;   // for phase 3 (16x16 fragments)
    const int m16  = lane & 15;
    const int h    = lane >> 5;   // K-half for 32x32 fragments
    const int l32  = lane & 31;
    const int l16  = lane & 15;
    const int hb   = l32 >> 4;    // 16-row within 32-col group

    // ---- stage x into LDS as f16 (row-major; transpose built later) ----
    const float4* xg4 = (const float4*)(emb + (size_t)b * NF * EDIM);
    #pragma unroll
    for (int it = 0; it < 4; ++it) {
        int idx = t + it * 256;
        int f = idx >> 4, e4 = (idx & 15) * 4;
        float4 v = xg4[idx];
        f16x2 p0 = pkrtz(v.x, v.y);
        f16x2 p1 = pkrtz(v.z, v.w);
        f16x4 pk = {p0.x, p0.y, p1.x, p1.y};
        *(f16x4*)&xs[f * XSTR + e4] = pk;
    }

    // ---- W1^T A-fragments for 32x32x16: A[m=adim=l32][k=8h+jj] ----
    f16x8 w1a[4];
    #pragma unroll
    for (int q = 0; q < 4; ++q)
        #pragma unroll
        for (int jj = 0; jj < 8; jj += 2) {
            float fa = W1[(16 * q + 8 * h + jj)     * ADIM + l32];
            float fb = W1[(16 * q + 8 * h + jj + 1) * ADIM + l32];
            f16x2 pk = pkrtz(fa, fb);
            w1a[q][jj] = pk.x; w1a[q][jj + 1] = pk.y;
        }

    // b1/W2 as packed f32x2 pairs in C/D row order: a(r) = (r&3)+8*(r>>2)+4h
    f32x2 b1f2[8], w2f2[8];
    #pragma unroll
    for (int rr = 0; rr < 8; ++rr) {
        int r = 2 * rr;
        int a = (r & 3) + 8 * (r >> 2) + 4 * h;
        b1f2[rr] = (f32x2){b1[a], b1[a + 1]};
        w2f2[rr] = (f32x2){W2[a], W2[a + 1]};
    }
    const float b2s = b2[0];
    __syncthreads();

    // ---- build Xt via read-transpose (conflict-free both sides) ----
    {
        const unsigned short* xsu = (const unsigned short*)xs;
        #pragma unroll
        for (int it = 0; it < 2; ++it) {
            int cid = t + it * 256;
            int e = cid & 63, c = cid >> 6;     // e = lane, c uniform per wave
            unsigned int d[4];
            #pragma unroll
            for (int r2 = 0; r2 < 4; ++r2) {
                unsigned lo = xsu[(8 * c + 2 * r2)     * XSTR + e];
                unsigned hi = xsu[(8 * c + 2 * r2 + 1) * XSTR + e];
                d[r2] = lo | (hi << 16);
            }
            int4 w4 = {(int)d[0], (int)d[1], (int)d[2], (int)d[3]};
            *(int4*)&Xt[e * XSTR + 8 * c] = w4;
        }
    }
    __syncthreads();

    // ---- DPP direction probe: jv registers rotate WITH the data ----
    int probe = __builtin_amdgcn_mov_dpp(l16, 0x124, 0xF, 0xF, false);
    const bool plus4 = (probe == ((l16 + 4) & 15));
    const int  s0r   = plus4 ? (wid + 1) : (wid + 5);

    // ---- phase 1: exp(logit) via 32x32x16 MFMA, register rows + DPP ----
    int4 xi4[4], xj4[4];

    auto LOADX = [&](int row, int4* d) {
        #pragma unroll
        for (int q = 0; q < 4; ++q)
            d[q] = *(const int4*)&xs[row * XSTR + 16 * q + 8 * h];
    };
    auto ROT4D = [&](int4* d, int& jv) {   // rotate data AND its row index
        #pragma unroll
        for (int q = 0; q < 4; ++q) {
            d[q].x = __builtin_amdgcn_mov_dpp(d[q].x, 0x124, 0xF, 0xF, false);
            d[q].y = __builtin_amdgcn_mov_dpp(d[q].y, 0x124, 0xF, 0xF, false);
            d[q].z = __builtin_amdgcn_mov_dpp(d[q].z, 0x124, 0xF, 0xF, false);
            d[q].w = __builtin_amdgcn_mov_dpp(d[q].w, 0x124, 0xF, 0xF, false);
        }
        jv = __builtin_amdgcn_mov_dpp(jv, 0x124, 0xF, 0xF, false);
    };
    auto SUB = [&](const int4* xa, const int4* xb, int iv, int jv) {
        f32x16 acc = {};
        #pragma unroll
        for (int q = 0; q < 4; ++q) {
            f16x8 prod = asH(xa[q]) * asH(xb[q]);   // v_pk_mul_f16 x4
            acc = __builtin_amdgcn_mfma_f32_32x32x16_f16(w1a[q], prod, acc, 0, 0, 0);
        }
        f32x2 tr2 = {0.f, 0.f};
        #pragma unroll
        for (int rr = 0; rr < 8; ++rr) {
            f32x2 a2 = {acc[2 * rr], acc[2 * rr + 1]};
            f32x2 h2 = __builtin_elementwise_max(a2 + b1f2[rr], (f32x2){0.f, 0.f});
            tr2 += h2 * w2f2[rr];
        }
        float tr = tr2.x + tr2.y;
        tr += __shfl_xor(tr, 32);
        // Unnormalized softmax numerator; logits bounded (~|4|) so exp is safe
        // in f32 and f16 (e^11 is the f16 limit). Normalization folded later.
        float ev = __expf(tr + b2s);
        int imin = min(iv, jv), jmax = max(iv, jv);
        int p = ((imin * (127 - imin)) >> 1) + jmax - imin - 1;
        if (lane < 32) {
            logits[p] = ev;
            f16 ah = (f16)ev;
            As[imin * ASTR + jmax] = ah;
            As[jmax * ASTR + imin] = ah;
        }
    };

    LOADX(l32, xi4);
    {   // off-diag (0,1) pattern A
        int jv = 32 + 16 * hb + ((l16 + wid) & 15);
        LOADX(jv, xj4);
        #pragma unroll
        for (int k = 0; k < 4; ++k) {
            SUB(xi4, xj4, l32, jv);
            if (k < 3) ROT4D(xj4, jv);
        }
    }
    {   // off-diag (0,1) pattern B
        int jv = 32 + 16 * (1 - hb) + ((l16 + wid) & 15);
        LOADX(jv, xj4);
        #pragma unroll
        for (int k = 0; k < 4; ++k) {
            SUB(xi4, xj4, l32, jv);
            if (k < 3) ROT4D(xj4, jv);
        }
    }
    {   // diag (0,0) ring
        int jv = 16 * hb + ((l16 + s0r) & 15);
        LOADX(jv, xj4);
        SUB(xi4, xj4, l32, jv);
        ROT4D(xj4, jv);
        SUB(xi4, xj4, l32, jv);
    }
    {   // diag (0,0) cross
        int jv = 16 + ((l16 + wid + 8 * hb) & 15);
        LOADX(l16, xi4);
        LOADX(jv, xj4);
        SUB(xi4, xj4, l16, jv);
        ROT4D(xj4, jv);
        SUB(xi4, xj4, l16, jv);
    }
    {   // diag (1,1) ring
        int jv = 32 + 16 * hb + ((l16 + s0r) & 15);
        LOADX(32 + l32, xi4);
        LOADX(jv, xj4);
        SUB(xi4, xj4, 32 + l32, jv);
        ROT4D(xj4, jv);
        SUB(xi4, xj4, 32 + l32, jv);
    }
    {   // diag (1,1) cross
        int jv = 48 + ((l16 + wid + 8 * hb) & 15);
        LOADX(32 + l16, xi4);
        LOADX(jv, xj4);
        SUB(xi4, xj4, 32 + l16, jv);
        ROT4D(xj4, jv);
        SUB(xi4, xj4, 32 + l16, jv);
    }
    if (t < NF) As[t * ASTR + t] = (f16)0.f;   // zero diagonal (i != j in SUBs)
    __syncthreads();

    // ---- phase 2: just a SUM reduction (no max pass, no exp pass) ----
    float lv[8];
    #pragma unroll
    for (int k = 0; k < 8; ++k) {
        int p = t + 256 * k;
        lv[k] = (p < NPAIR) ? logits[p] : 0.f;
    }
    float sw = 0.f;
    #pragma unroll
    for (int k = 0; k < 8; ++k) sw += lv[k];
    #pragma unroll
    for (int off = 32; off; off >>= 1) sw += __shfl_xor(sw, off);
    if (lane == 0) red[wid] = sw;
    __syncthreads();
    const float inv = 1.0f / (red[0] + red[1] + red[2] + red[3]);

    #pragma unroll
    for (int k = 0; k < 8; ++k) {
        int p = t + 256 * k;
        if (p < NPAIR) out_attn[(size_t)b * NPAIR + p] = lv[k] * inv;
    }

    // ---- phase 3: Y = E @ X via MFMA; out[e] = 0.5*inv * sum_i X[i,e] Y[i,e] ----
    const int itile = wid;          // each wave owns 16 rows of E
    const f16* arow = &As[(itile * 16 + m16) * ASTR];   // rows fully written pre-barrier
    f16x4 afa0 = *(const f16x4*)(arow + 8 * g);
    f16x4 afb0 = *(const f16x4*)(arow + 8 * g + 4);
    f16x4 afa1 = *(const f16x4*)(arow + 32 + 8 * g);
    f16x4 afb1 = *(const f16x4*)(arow + 32 + 8 * g + 4);
    f16x8 af0, af1;
    #pragma unroll
    for (int j = 0; j < 4; ++j) {
        af0[j] = afa0[j]; af0[4 + j] = afb0[j];
        af1[j] = afa1[j]; af1[4 + j] = afb1[j];
    }

    f32x4 yacc[4];
    #pragma unroll
    for (int et = 0; et < 4; ++et) yacc[et] = (f32x4){0.f, 0.f, 0.f, 0.f};
    #pragma unroll
    for (int et = 0; et < 4; ++et) {
        const f16* xtr = &Xt[(et * 16 + m16) * XSTR];
        f16x8 bf0 = *(const f16x8*)(xtr + 8 * g);
        f16x8 bf1 = *(const f16x8*)(xtr + 32 + 8 * g);
        yacc[et] = __builtin_amdgcn_mfma_f32_16x16x32_f16(af0, bf0, yacc[et], 0, 0, 0);
        yacc[et] = __builtin_amdgcn_mfma_f32_16x16x32_f16(af1, bf1, yacc[et], 0, 0, 0);
    }

    #pragma unroll
    for (int et = 0; et < 4; ++et) {
        float v = 0.f;
        #pragma unroll
        for (int r = 0; r < 4; ++r) {
            int i = itile * 16 + 4 * g + r;
            int e = et * 16 + m16;
            v = fmaf((float)xs[i * XSTR + e], yacc[et][r], v);
        }
        v += __shfl_xor(v, 16);
        v += __shfl_xor(v, 32);
        if (g == 0) partial[wid][et * 16 + m16] = v;
    }
    __syncthreads();
    if (t < EDIM)
        out_vec[(size_t)b * EDIM + t] = 0.5f * inv *
            (partial[0][t] + partial[1][t] + partial[2][t] + partial[3][t]);
}

extern "C" void kernel_launch(void* const* d_in, const int* in_sizes, int n_in,
                              void* d_out, int out_size, void* d_ws, size_t ws_size,
                              hipStream_t stream) {
    const float* emb = (const float*)d_in[0];
    const float* W1  = (const float*)d_in[1];
    const float* b1  = (const float*)d_in[2];
    const float* W2  = (const float*)d_in[3];
    const float* b2  = (const float*)d_in[4];
    float* out_vec  = (float*)d_out;                        // (B, E)
    float* out_attn = (float*)d_out + (size_t)BATCH * EDIM; // (B, NPAIR)

    afm_kernel<<<BATCH, 256, 0, stream>>>(emb, W1, b1, W2, b2, out_vec, out_attn);
}